// Round 1
// baseline (331.092 us; speedup 1.0000x reference)
//
#include <hip/hip_runtime.h>
#include <stdint.h>

#define NQ 4096
#define NCAM 6
#define NV 22050
#define M_TOTAL (NCAM * NV) /* 132300 */

typedef __bf16 bf16x8 __attribute__((ext_vector_type(8)));
typedef float f32x4 __attribute__((ext_vector_type(4)));
typedef unsigned int u32x4 __attribute__((ext_vector_type(4)));

__device__ __forceinline__ unsigned short f2bf(float f) {
    union { float f; uint32_t u; } v; v.f = f;
    uint32_t u = v.u;
    uint32_t r = (u + 0x7FFFu + ((u >> 16) & 1u)) >> 16;
    return (unsigned short)r;
}
__device__ __forceinline__ float bf2f(unsigned short b) {
    union { uint32_t u; float f; } v; v.u = ((uint32_t)b) << 16;
    return v.f;
}
__device__ __forceinline__ int imin(int a, int b) { return a < b ? a : b; }
__device__ __forceinline__ int imax(int a, int b) { return a > b ? a : b; }

// ---------------- Wv transpose + bf16 convert (tiny) ----------------
__global__ void wvt_kernel(const float* __restrict__ Wv, unsigned short* __restrict__ WvT) {
    int n = blockIdx.x, k = threadIdx.x;
    WvT[n * 256 + k] = f2bf(Wv[k * 256 + n]);
}

// ---------------- value projection GEMM: val = value @ Wv + bv (bf16 MFMA) ----------------
// A: value (M_TOTAL, 256) f32 row-major. BT: WvT bf16 (256 n, 256 k). C: val bf16 (M_TOTAL, 256).
__global__ __launch_bounds__(256) void val_gemm(const float* __restrict__ A,
                                                const unsigned short* __restrict__ BT,
                                                const float* __restrict__ bv,
                                                unsigned short* __restrict__ C) {
    __shared__ unsigned char Asm[64 * 80];   // 64 rows x 32 k bf16, row stride 80B (pad)
    __shared__ unsigned char Bsm[256 * 80];  // 256 n x 32 k bf16, row stride 80B
    const int t = threadIdx.x;
    const int wave = t >> 6, lane = t & 63;
    const int m_base = blockIdx.x * 64;

    f32x4 acc[4][4];
#pragma unroll
    for (int i = 0; i < 4; ++i)
#pragma unroll
        for (int j = 0; j < 4; ++j) acc[i][j] = (f32x4)0.0f;

    const int rsel = lane & 15, g = lane >> 4;

    for (int k0 = 0; k0 < 256; k0 += 32) {
        __syncthreads();
        // stage A: 64 rows x 32 k, f32 -> bf16. 512 chunks of 4 f32.
#pragma unroll
        for (int it = 0; it < 2; ++it) {
            int cc = t + it * 256;
            int r = cc >> 3, ck = cc & 7;
            int gr = imin(m_base + r, M_TOTAL - 1);
            float4 v = *reinterpret_cast<const float4*>(A + (size_t)gr * 256 + k0 + ck * 4);
            uint2 pk;
            pk.x = (uint32_t)f2bf(v.x) | ((uint32_t)f2bf(v.y) << 16);
            pk.y = (uint32_t)f2bf(v.z) | ((uint32_t)f2bf(v.w) << 16);
            *reinterpret_cast<uint2*>(&Asm[r * 80 + ck * 8]) = pk;
        }
        // stage B: 256 n x 32 k bf16. 1024 chunks of 16B.
#pragma unroll
        for (int it = 0; it < 4; ++it) {
            int cc = t + it * 256;
            int n = cc >> 2, ck = cc & 3;
            u32x4 v = *reinterpret_cast<const u32x4*>(BT + n * 256 + k0 + ck * 8);
            *reinterpret_cast<u32x4*>(&Bsm[n * 80 + ck * 16]) = v;
        }
        __syncthreads();

        bf16x8 af[4], bfr[4];
#pragma unroll
        for (int mi = 0; mi < 4; ++mi)
            af[mi] = __builtin_bit_cast(bf16x8,
                *reinterpret_cast<const u32x4*>(&Asm[(mi * 16 + rsel) * 80 + g * 16]));
#pragma unroll
        for (int ni = 0; ni < 4; ++ni)
            bfr[ni] = __builtin_bit_cast(bf16x8,
                *reinterpret_cast<const u32x4*>(&Bsm[(wave * 64 + ni * 16 + rsel) * 80 + g * 16]));
#pragma unroll
        for (int mi = 0; mi < 4; ++mi)
#pragma unroll
            for (int ni = 0; ni < 4; ++ni)
                acc[mi][ni] = __builtin_amdgcn_mfma_f32_16x16x32_bf16(af[mi], bfr[ni], acc[mi][ni], 0, 0, 0);
    }

    // epilogue: + bias, -> bf16, store. C/D layout: col = lane&15, row = (lane>>4)*4 + j.
#pragma unroll
    for (int ni = 0; ni < 4; ++ni) {
        int n = wave * 64 + ni * 16 + rsel;
        float bvv = bv[n];
#pragma unroll
        for (int mi = 0; mi < 4; ++mi)
#pragma unroll
            for (int j = 0; j < 4; ++j) {
                int m = m_base + mi * 16 + g * 4 + j;
                if (m < M_TOTAL) C[(size_t)m * 256 + n] = f2bf(acc[mi][ni][j] + bvv);
            }
    }
}

// ---------------- offsets + attention weights (q-only, cam-independent) ----------------
// off_ws[q][384] = (q@Ws + b_off) / norm(level);  aw_ws[q][8][24] = softmax over 24.
__global__ __launch_bounds__(256) void proj_kernel(const float* __restrict__ query,
                                                   const float* __restrict__ qpos,
                                                   const float* __restrict__ Ws,
                                                   const float* __restrict__ b_off,
                                                   const float* __restrict__ Wa,
                                                   const float* __restrict__ ba,
                                                   float* __restrict__ off_ws,
                                                   float* __restrict__ aw_ws) {
    __shared__ float qrow[4][256];
    __shared__ float logits[4][192];
    const int t = threadIdx.x;
    const int qb = blockIdx.x * 4;
#pragma unroll
    for (int j = 0; j < 4; ++j)
        qrow[j][t] = query[(size_t)(qb + j) * 256 + t] + qpos[(size_t)(qb + j) * 256 + t];
    __syncthreads();

    const float invn[3][2] = {{1.f / 168.f, 1.f / 100.f},
                              {1.f / 84.f, 1.f / 50.f},
                              {1.f / 42.f, 1.f / 25.f}};
#pragma unroll
    for (int pass = 0; pass < 3; ++pass) {
        int u = t + pass * 256;
        if (u < 384) {
            float a0 = 0.f, a1 = 0.f, a2 = 0.f, a3 = 0.f;
            for (int k = 0; k < 256; ++k) {
                float w = Ws[k * 384 + u];
                a0 += qrow[0][k] * w; a1 += qrow[1][k] * w;
                a2 += qrow[2][k] * w; a3 += qrow[3][k] * w;
            }
            int lp = u >> 1;               // (h*3+l)*8+p
            int l = (lp >> 3) % 3;
            float inv = invn[l][u & 1];
            float b = b_off[u];
            off_ws[(size_t)(qb + 0) * 384 + u] = (a0 + b) * inv;
            off_ws[(size_t)(qb + 1) * 384 + u] = (a1 + b) * inv;
            off_ws[(size_t)(qb + 2) * 384 + u] = (a2 + b) * inv;
            off_ws[(size_t)(qb + 3) * 384 + u] = (a3 + b) * inv;
        } else if (u < 576) {
            int u2 = u - 384;
            float a0 = 0.f, a1 = 0.f, a2 = 0.f, a3 = 0.f;
            for (int k = 0; k < 256; ++k) {
                float w = Wa[k * 192 + u2];
                a0 += qrow[0][k] * w; a1 += qrow[1][k] * w;
                a2 += qrow[2][k] * w; a3 += qrow[3][k] * w;
            }
            float b = ba[u2];
            logits[0][u2] = a0 + b; logits[1][u2] = a1 + b;
            logits[2][u2] = a2 + b; logits[3][u2] = a3 + b;
        }
    }
    __syncthreads();
    if (t < 32) {
        int jq = t >> 3, h = t & 7;
        float mx = -1e30f;
#pragma unroll
        for (int i = 0; i < 24; ++i) mx = fmaxf(mx, logits[jq][h * 24 + i]);
        float e[24];
        float s = 0.f;
#pragma unroll
        for (int i = 0; i < 24; ++i) { e[i] = __expf(logits[jq][h * 24 + i] - mx); s += e[i]; }
        float inv = 1.0f / s;
#pragma unroll
        for (int i = 0; i < 24; ++i)
            aw_ws[((size_t)(qb + jq) * 8 + h) * 24 + i] = e[i] * inv;
    }
}

// ---------------- bilinear sampling + attention-weighted accumulation ----------------
__device__ __forceinline__ float fetch_corner(const unsigned short* __restrict__ vcam,
                                              int st, int xi, int yi, int w, int hh) {
    bool valid = (xi >= 0) & (xi < w) & (yi >= 0) & (yi < hh);
    int xc = imin(imax(xi, 0), w - 1);
    int yc = imin(imax(yi, 0), hh - 1);
    float v = bf2f(vcam[(size_t)(st + yc * w + xc) * 256]);
    return valid ? v : 0.f;
}

__global__ __launch_bounds__(256) void sample_kernel(const unsigned short* __restrict__ val,
                                                     const float* __restrict__ rpc,
                                                     const float* __restrict__ off_ws,
                                                     const float* __restrict__ aw_ws,
                                                     float* __restrict__ out_cam) {
    const int t = threadIdx.x;
    const int h = t >> 5, d = t & 31;
    const int q = blockIdx.x, c = blockIdx.y;
    const int lw[3] = {168, 84, 42};
    const int lh[3] = {100, 50, 25};
    const int lstart[3] = {0, 16800, 21000};

    float refx[4], refy[4];
#pragma unroll
    for (int a = 0; a < 4; ++a) {
        refx[a] = rpc[((size_t)c * NQ + q) * 8 + a * 2 + 0];
        refy[a] = rpc[((size_t)c * NQ + q) * 8 + a * 2 + 1];
    }
    const unsigned short* vcam = val + (size_t)c * NV * 256 + h * 32 + d;

    float acc = 0.f;
#pragma unroll
    for (int l = 0; l < 3; ++l) {
        const float wl = (float)lw[l], hlv = (float)lh[l];
        const int st = lstart[l];
#pragma unroll
        for (int p = 0; p < 8; ++p) {
            int a = p & 3;
            float ox = off_ws[(size_t)q * 384 + (size_t)((h * 3 + l) * 8 + p) * 2 + 0];
            float oy = off_ws[(size_t)q * 384 + (size_t)((h * 3 + l) * 8 + p) * 2 + 1];
            float x = (refx[a] + ox) * wl - 0.5f;
            float y = (refy[a] + oy) * hlv - 0.5f;
            float x0f = floorf(x), y0f = floorf(y);
            float lx = x - x0f, ly = y - y0f;
            int x0 = (int)x0f, y0 = (int)y0f;
            float aww = aw_ws[((size_t)q * 8 + h) * 24 + l * 8 + p];
            float v00 = fetch_corner(vcam, st, x0,     y0,     lw[l], lh[l]);
            float v10 = fetch_corner(vcam, st, x0 + 1, y0,     lw[l], lh[l]);
            float v01 = fetch_corner(vcam, st, x0,     y0 + 1, lw[l], lh[l]);
            float v11 = fetch_corner(vcam, st, x0 + 1, y0 + 1, lw[l], lh[l]);
            float bil = v00 * (1.f - lx) * (1.f - ly) + v10 * lx * (1.f - ly) +
                        v01 * (1.f - lx) * ly + v11 * lx * ly;
            acc += aww * bil;
        }
    }
    out_cam[((size_t)c * NQ + q) * 256 + t] = acc;
}

// ---------------- mask-combine over cams + output projection + residual ----------------
__global__ __launch_bounds__(256) void combine_kernel(const float* __restrict__ out_cam,
                                                      const unsigned char* __restrict__ bev_mask,
                                                      const float* __restrict__ Wo,
                                                      const float* __restrict__ bo,
                                                      const float* __restrict__ query,
                                                      float* __restrict__ out) {
    __shared__ float s_lds[8][256];
    __shared__ unsigned int hitm[8];
    __shared__ float invc[8];
    const int t = threadIdx.x;
    const int qb = blockIdx.x * 8;

    if (t < 8) {
        int q = qb + t;
        unsigned int m = 0;
        int cnt = 0;
        for (int c = 0; c < 6; ++c) {
            const unsigned char* bm = bev_mask + ((size_t)c * NQ + q) * 4;
            if (bm[0] | bm[1] | bm[2] | bm[3]) { m |= (1u << c); cnt++; }
        }
        hitm[t] = m;
        invc[t] = 1.0f / (float)imax(cnt, 1);
    }
    __syncthreads();
#pragma unroll
    for (int j = 0; j < 8; ++j) {
        unsigned int m = hitm[j];
        float ic = invc[j];
        float s = 0.f;
#pragma unroll
        for (int c = 0; c < 6; ++c)
            if ((m >> c) & 1u) s += out_cam[((size_t)c * NQ + qb + j) * 256 + t];
        s_lds[j][t] = s * ic;
    }
    __syncthreads();
    float acc[8] = {0.f, 0.f, 0.f, 0.f, 0.f, 0.f, 0.f, 0.f};
    for (int k = 0; k < 256; ++k) {
        float wv = Wo[k * 256 + t];
#pragma unroll
        for (int j = 0; j < 8; ++j) acc[j] += s_lds[j][k] * wv;
    }
    float bb = bo[t];
#pragma unroll
    for (int j = 0; j < 8; ++j)
        out[(size_t)(qb + j) * 256 + t] = acc[j] + bb + query[(size_t)(qb + j) * 256 + t];
}

extern "C" void kernel_launch(void* const* d_in, const int* in_sizes, int n_in,
                              void* d_out, int out_size, void* d_ws, size_t ws_size,
                              hipStream_t stream) {
    const float* query = (const float*)d_in[0];
    const float* value = (const float*)d_in[2];
    const float* qpos = (const float*)d_in[3];
    const float* rpc = (const float*)d_in[4];
    const unsigned char* bev = (const unsigned char*)d_in[5];
    const float* Wv = (const float*)d_in[8];
    const float* bv = (const float*)d_in[9];
    const float* Ws = (const float*)d_in[10];
    const float* b_off = (const float*)d_in[11];
    const float* Wa = (const float*)d_in[12];
    const float* ba = (const float*)d_in[13];
    const float* Wo = (const float*)d_in[14];
    const float* bo = (const float*)d_in[15];
    float* out = (float*)d_out;

    char* ws = (char*)d_ws;
    unsigned short* val_ws = (unsigned short*)ws;                        // 67,737,600 B
    size_t o = 67737600;
    float* off_ws = (float*)(ws + o);            o += 6291456;           // 4096*384*4
    float* aw_ws = (float*)(ws + o);             o += 3145728;           // 4096*192*4
    float* out_cam = (float*)(ws + o);           o += 25165824;          // 6*4096*256*4
    unsigned short* WvT = (unsigned short*)(ws + o);                     // 131,072 B

    wvt_kernel<<<256, 256, 0, stream>>>(Wv, WvT);
    proj_kernel<<<NQ / 4, 256, 0, stream>>>(query, qpos, Ws, b_off, Wa, ba, off_ws, aw_ws);
    val_gemm<<<(M_TOTAL + 63) / 64, 256, 0, stream>>>(value, WvT, bv, val_ws);
    sample_kernel<<<dim3(NQ, NCAM), 256, 0, stream>>>(val_ws, rpc, off_ws, aw_ws, out_cam);
    combine_kernel<<<NQ / 8, 256, 0, stream>>>(out_cam, bev, Wo, bo, query, out);
}

// Round 2
// 296.855 us; speedup vs baseline: 1.1153x; 1.1153x over previous
//
#include <hip/hip_runtime.h>
#include <stdint.h>

#define NQ 4096
#define NCAM 6
#define NV 22050
#define M_TOTAL (NCAM * NV) /* 132300 */

typedef __bf16 bf16x8 __attribute__((ext_vector_type(8)));
typedef float f32x4 __attribute__((ext_vector_type(4)));
typedef unsigned int u32x4 __attribute__((ext_vector_type(4)));

__device__ __forceinline__ unsigned short f2bf(float f) {
    union { float f; uint32_t u; } v; v.f = f;
    uint32_t u = v.u;
    uint32_t r = (u + 0x7FFFu + ((u >> 16) & 1u)) >> 16;
    return (unsigned short)r;
}
__device__ __forceinline__ float bf_lo(uint32_t u) {
    union { uint32_t u; float f; } v; v.u = u << 16; return v.f;
}
__device__ __forceinline__ float bf_hi(uint32_t u) {
    union { uint32_t u; float f; } v; v.u = u & 0xFFFF0000u; return v.f;
}
__device__ __forceinline__ int imin(int a, int b) { return a < b ? a : b; }
__device__ __forceinline__ int imax(int a, int b) { return a > b ? a : b; }

// ---------------- Wv transpose + bf16 convert (tiny) ----------------
__global__ void wvt_kernel(const float* __restrict__ Wv, unsigned short* __restrict__ WvT) {
    int n = blockIdx.x, k = threadIdx.x;
    WvT[n * 256 + k] = f2bf(Wv[k * 256 + n]);
}

// ---------------- value projection GEMM: val = value @ Wv + bv (bf16 MFMA) ----------------
__global__ __launch_bounds__(256) void val_gemm(const float* __restrict__ A,
                                                const unsigned short* __restrict__ BT,
                                                const float* __restrict__ bv,
                                                unsigned short* __restrict__ C) {
    __shared__ unsigned char Asm[64 * 80];   // 64 rows x 32 k bf16, row stride 80B (pad)
    __shared__ unsigned char Bsm[256 * 80];  // 256 n x 32 k bf16, row stride 80B
    const int t = threadIdx.x;
    const int wave = t >> 6, lane = t & 63;
    const int m_base = blockIdx.x * 64;

    f32x4 acc[4][4];
#pragma unroll
    for (int i = 0; i < 4; ++i)
#pragma unroll
        for (int j = 0; j < 4; ++j) acc[i][j] = (f32x4)0.0f;

    const int rsel = lane & 15, g = lane >> 4;

    for (int k0 = 0; k0 < 256; k0 += 32) {
        __syncthreads();
#pragma unroll
        for (int it = 0; it < 2; ++it) {
            int cc = t + it * 256;
            int r = cc >> 3, ck = cc & 7;
            int gr = imin(m_base + r, M_TOTAL - 1);
            float4 v = *reinterpret_cast<const float4*>(A + (size_t)gr * 256 + k0 + ck * 4);
            uint2 pk;
            pk.x = (uint32_t)f2bf(v.x) | ((uint32_t)f2bf(v.y) << 16);
            pk.y = (uint32_t)f2bf(v.z) | ((uint32_t)f2bf(v.w) << 16);
            *reinterpret_cast<uint2*>(&Asm[r * 80 + ck * 8]) = pk;
        }
#pragma unroll
        for (int it = 0; it < 4; ++it) {
            int cc = t + it * 256;
            int n = cc >> 2, ck = cc & 3;
            u32x4 v = *reinterpret_cast<const u32x4*>(BT + n * 256 + k0 + ck * 8);
            *reinterpret_cast<u32x4*>(&Bsm[n * 80 + ck * 16]) = v;
        }
        __syncthreads();

        bf16x8 af[4], bfr[4];
#pragma unroll
        for (int mi = 0; mi < 4; ++mi)
            af[mi] = __builtin_bit_cast(bf16x8,
                *reinterpret_cast<const u32x4*>(&Asm[(mi * 16 + rsel) * 80 + g * 16]));
#pragma unroll
        for (int ni = 0; ni < 4; ++ni)
            bfr[ni] = __builtin_bit_cast(bf16x8,
                *reinterpret_cast<const u32x4*>(&Bsm[(wave * 64 + ni * 16 + rsel) * 80 + g * 16]));
#pragma unroll
        for (int mi = 0; mi < 4; ++mi)
#pragma unroll
            for (int ni = 0; ni < 4; ++ni)
                acc[mi][ni] = __builtin_amdgcn_mfma_f32_16x16x32_bf16(af[mi], bfr[ni], acc[mi][ni], 0, 0, 0);
    }

#pragma unroll
    for (int ni = 0; ni < 4; ++ni) {
        int n = wave * 64 + ni * 16 + rsel;
        float bvv = bv[n];
#pragma unroll
        for (int mi = 0; mi < 4; ++mi)
#pragma unroll
            for (int j = 0; j < 4; ++j) {
                int m = m_base + mi * 16 + g * 4 + j;
                if (m < M_TOTAL) C[(size_t)m * 256 + n] = f2bf(acc[mi][ni][j] + bvv);
            }
    }
}

// ---------------- offsets + attention weights (q-only, cam-independent) ----------------
__global__ __launch_bounds__(256) void proj_kernel(const float* __restrict__ query,
                                                   const float* __restrict__ qpos,
                                                   const float* __restrict__ Ws,
                                                   const float* __restrict__ b_off,
                                                   const float* __restrict__ Wa,
                                                   const float* __restrict__ ba,
                                                   float* __restrict__ off_ws,
                                                   float* __restrict__ aw_ws) {
    __shared__ float qrow[4][256];
    __shared__ float logits[4][192];
    const int t = threadIdx.x;
    const int qb = blockIdx.x * 4;
#pragma unroll
    for (int j = 0; j < 4; ++j)
        qrow[j][t] = query[(size_t)(qb + j) * 256 + t] + qpos[(size_t)(qb + j) * 256 + t];
    __syncthreads();

    const float invn[3][2] = {{1.f / 168.f, 1.f / 100.f},
                              {1.f / 84.f, 1.f / 50.f},
                              {1.f / 42.f, 1.f / 25.f}};
#pragma unroll
    for (int pass = 0; pass < 3; ++pass) {
        int u = t + pass * 256;
        if (u < 384) {
            float a0 = 0.f, a1 = 0.f, a2 = 0.f, a3 = 0.f;
            for (int k = 0; k < 256; ++k) {
                float w = Ws[k * 384 + u];
                a0 += qrow[0][k] * w; a1 += qrow[1][k] * w;
                a2 += qrow[2][k] * w; a3 += qrow[3][k] * w;
            }
            int lp = u >> 1;               // (h*3+l)*8+p
            int l = (lp >> 3) % 3;
            float inv = invn[l][u & 1];
            float b = b_off[u];
            off_ws[(size_t)(qb + 0) * 384 + u] = (a0 + b) * inv;
            off_ws[(size_t)(qb + 1) * 384 + u] = (a1 + b) * inv;
            off_ws[(size_t)(qb + 2) * 384 + u] = (a2 + b) * inv;
            off_ws[(size_t)(qb + 3) * 384 + u] = (a3 + b) * inv;
        } else if (u < 576) {
            int u2 = u - 384;
            float a0 = 0.f, a1 = 0.f, a2 = 0.f, a3 = 0.f;
            for (int k = 0; k < 256; ++k) {
                float w = Wa[k * 192 + u2];
                a0 += qrow[0][k] * w; a1 += qrow[1][k] * w;
                a2 += qrow[2][k] * w; a3 += qrow[3][k] * w;
            }
            float b = ba[u2];
            logits[0][u2] = a0 + b; logits[1][u2] = a1 + b;
            logits[2][u2] = a2 + b; logits[3][u2] = a3 + b;
        }
    }
    __syncthreads();
    if (t < 32) {
        int jq = t >> 3, h = t & 7;
        float mx = -1e30f;
#pragma unroll
        for (int i = 0; i < 24; ++i) mx = fmaxf(mx, logits[jq][h * 24 + i]);
        float e[24];
        float s = 0.f;
#pragma unroll
        for (int i = 0; i < 24; ++i) { e[i] = __expf(logits[jq][h * 24 + i] - mx); s += e[i]; }
        float inv = 1.0f / s;
#pragma unroll
        for (int i = 0; i < 24; ++i)
            aw_ws[((size_t)(qb + jq) * 8 + h) * 24 + i] = e[i] * inv;
    }
}

// ---------------- bilinear sampling: 32 lanes per (q,c), 8 channels per lane ----------------
// lane = h*4 + sub; channels = h*32 + sub*8 .. +8. Corner fetch = dwordx4 (8 bf16).
// Validity folded into bilinear weights; aww premultiplied into y-weights.
__global__ __launch_bounds__(256) void sample_kernel(const unsigned short* __restrict__ val,
                                                     const float* __restrict__ rpc,
                                                     const float* __restrict__ off_ws,
                                                     const float* __restrict__ aw_ws,
                                                     float* __restrict__ out_cam) {
    const int t = threadIdx.x;
    const int grp = t >> 5;             // 8 (q,c) pairs per block
    const int lane = t & 31;
    const int h = lane >> 2;            // head
    const int sub = lane & 3;           // channel quad within head
    const int pair = blockIdx.x * 8 + grp;  // pair = c*NQ + q
    const int c = pair >> 12;
    const int q = pair & (NQ - 1);

    float refx[4], refy[4];
    const float* rp = rpc + (size_t)pair * 8;
#pragma unroll
    for (int a = 0; a < 4; ++a) { refx[a] = rp[2 * a]; refy[a] = rp[2 * a + 1]; }

    const int chb = h * 32 + sub * 8;
    const unsigned short* vbase = val + (size_t)c * NV * 256 + chb;
    const float* offp = off_ws + (size_t)q * 384 + h * 48;   // [l][p][2]
    const float* awp = aw_ws + ((size_t)q * 8 + h) * 24;

    float acc[8];
#pragma unroll
    for (int i = 0; i < 8; ++i) acc[i] = 0.f;

    const int lw[3] = {168, 84, 42};
    const int lhh[3] = {100, 50, 25};
    const int lst[3] = {0, 16800, 21000};

#pragma unroll
    for (int l = 0; l < 3; ++l) {
        const int w = lw[l], hh = lhh[l];
        const float wf = (float)w, hf = (float)hh;
        const unsigned short* vlev = vbase + (size_t)lst[l] * 256;
#pragma unroll
        for (int p = 0; p < 8; ++p) {
            const int a = p & 3;
            float ox = offp[(l * 8 + p) * 2 + 0];
            float oy = offp[(l * 8 + p) * 2 + 1];
            float x = fmaf(refx[a] + ox, wf, -0.5f);
            float y = fmaf(refy[a] + oy, hf, -0.5f);
            float xf = floorf(x), yf = floorf(y);
            float lx = x - xf, ly = y - yf;
            int x0 = (int)xf, y0 = (int)yf;
            float aww = awp[l * 8 + p];

            float wx0 = (x0 >= 0 && x0 < w) ? (1.f - lx) : 0.f;
            float wx1 = (x0 >= -1 && x0 < w - 1) ? lx : 0.f;
            float wy0 = ((y0 >= 0 && y0 < hh) ? (1.f - ly) : 0.f) * aww;
            float wy1 = ((y0 >= -1 && y0 < hh - 1) ? ly : 0.f) * aww;

            int x0c = imin(imax(x0, 0), w - 1);
            int x1c = imin(imax(x0 + 1, 0), w - 1);
            int y0c = imin(imax(y0, 0), hh - 1);
            int y1c = imin(imax(y0 + 1, 0), hh - 1);

            const unsigned short* r0 = vlev + (size_t)(y0c * w) * 256;
            const unsigned short* r1 = vlev + (size_t)(y1c * w) * 256;
            u32x4 u00 = *reinterpret_cast<const u32x4*>(r0 + (size_t)x0c * 256);
            u32x4 u10 = *reinterpret_cast<const u32x4*>(r0 + (size_t)x1c * 256);
            u32x4 u01 = *reinterpret_cast<const u32x4*>(r1 + (size_t)x0c * 256);
            u32x4 u11 = *reinterpret_cast<const u32x4*>(r1 + (size_t)x1c * 256);

            float w00 = wx0 * wy0, w10 = wx1 * wy0, w01 = wx0 * wy1, w11 = wx1 * wy1;
#pragma unroll
            for (int i = 0; i < 4; ++i) {
                acc[2 * i] += w00 * bf_lo(u00[i]) + w10 * bf_lo(u10[i]) +
                              w01 * bf_lo(u01[i]) + w11 * bf_lo(u11[i]);
                acc[2 * i + 1] += w00 * bf_hi(u00[i]) + w10 * bf_hi(u10[i]) +
                                  w01 * bf_hi(u01[i]) + w11 * bf_hi(u11[i]);
            }
        }
    }

    float4 o0 = make_float4(acc[0], acc[1], acc[2], acc[3]);
    float4 o1 = make_float4(acc[4], acc[5], acc[6], acc[7]);
    float* op = out_cam + (size_t)pair * 256 + chb;
    *reinterpret_cast<float4*>(op) = o0;
    *reinterpret_cast<float4*>(op + 4) = o1;
}

// ---------------- mask-combine over cams + output projection + residual ----------------
__global__ __launch_bounds__(256) void combine_kernel(const float* __restrict__ out_cam,
                                                      const unsigned char* __restrict__ bev_mask,
                                                      const float* __restrict__ Wo,
                                                      const float* __restrict__ bo,
                                                      const float* __restrict__ query,
                                                      float* __restrict__ out) {
    __shared__ float s_lds[8][256];
    __shared__ unsigned int hitm[8];
    __shared__ float invc[8];
    const int t = threadIdx.x;
    const int qb = blockIdx.x * 8;

    if (t < 8) {
        int q = qb + t;
        unsigned int m = 0;
        int cnt = 0;
        for (int c = 0; c < 6; ++c) {
            const unsigned char* bm = bev_mask + ((size_t)c * NQ + q) * 4;
            if (bm[0] | bm[1] | bm[2] | bm[3]) { m |= (1u << c); cnt++; }
        }
        hitm[t] = m;
        invc[t] = 1.0f / (float)imax(cnt, 1);
    }
    __syncthreads();
#pragma unroll
    for (int j = 0; j < 8; ++j) {
        unsigned int m = hitm[j];
        float ic = invc[j];
        float s = 0.f;
#pragma unroll
        for (int c = 0; c < 6; ++c)
            if ((m >> c) & 1u) s += out_cam[((size_t)c * NQ + qb + j) * 256 + t];
        s_lds[j][t] = s * ic;
    }
    __syncthreads();
    float acc[8] = {0.f, 0.f, 0.f, 0.f, 0.f, 0.f, 0.f, 0.f};
    for (int k = 0; k < 256; ++k) {
        float wv = Wo[k * 256 + t];
#pragma unroll
        for (int j = 0; j < 8; ++j) acc[j] += s_lds[j][k] * wv;
    }
    float bb = bo[t];
#pragma unroll
    for (int j = 0; j < 8; ++j)
        out[(size_t)(qb + j) * 256 + t] = acc[j] + bb + query[(size_t)(qb + j) * 256 + t];
}

extern "C" void kernel_launch(void* const* d_in, const int* in_sizes, int n_in,
                              void* d_out, int out_size, void* d_ws, size_t ws_size,
                              hipStream_t stream) {
    const float* query = (const float*)d_in[0];
    const float* value = (const float*)d_in[2];
    const float* qpos = (const float*)d_in[3];
    const float* rpc = (const float*)d_in[4];
    const unsigned char* bev = (const unsigned char*)d_in[5];
    const float* Wv = (const float*)d_in[8];
    const float* bv = (const float*)d_in[9];
    const float* Ws = (const float*)d_in[10];
    const float* b_off = (const float*)d_in[11];
    const float* Wa = (const float*)d_in[12];
    const float* ba = (const float*)d_in[13];
    const float* Wo = (const float*)d_in[14];
    const float* bo = (const float*)d_in[15];
    float* out = (float*)d_out;

    char* ws = (char*)d_ws;
    unsigned short* val_ws = (unsigned short*)ws;                        // 67,737,600 B
    size_t o = 67737600;
    float* off_ws = (float*)(ws + o);            o += 6291456;           // 4096*384*4
    float* aw_ws = (float*)(ws + o);             o += 3145728;           // 4096*192*4
    float* out_cam = (float*)(ws + o);           o += 25165824;          // 6*4096*256*4
    unsigned short* WvT = (unsigned short*)(ws + o);                     // 131,072 B

    wvt_kernel<<<256, 256, 0, stream>>>(Wv, WvT);
    proj_kernel<<<NQ / 4, 256, 0, stream>>>(query, qpos, Ws, b_off, Wa, ba, off_ws, aw_ws);
    val_gemm<<<(M_TOTAL + 63) / 64, 256, 0, stream>>>(value, WvT, bv, val_ws);
    sample_kernel<<<(NQ * NCAM) / 8, 256, 0, stream>>>(val_ws, rpc, off_ws, aw_ws, out_cam);
    combine_kernel<<<NQ / 8, 256, 0, stream>>>(out_cam, bev, Wo, bo, query, out);
}